// Round 12
// baseline (34.813 us; speedup 1.0000x reference)
//
#include <hip/hip_runtime.h>
#include <math.h>

#define N_RAYS 16384
#define S 128
#define FEAT 15
#define BOUNDF 2.0f
#define MIN_NEAR 0.05f
#define RPB 4              // rays (waves) per 256-thread block
#define PRW 1232           // per-ray LDS words (4928 B)

// per-ray LDS word offsets — aliasing sequenced by single-wave in-order DS ops:
//   stg (f16-packed, 0..329)  live during each MLP pass + readback
//   cdf 0..127                written after coarse readback (stg cols 0-1 dead),
//                             consumed in lerp before fine pass rewrites stg
//   HU 336..467, HM 468..599  zeroed at start (outside stg), consumed before
//                             the sorted scatter (writes 0..1023) begins
//   zsg 0..511, rgb 512..1023 sorted arrays, written last
//   zf 1024..1151, AB 1152.., BIAS 1216..  un-aliased
#define O_STG  0
#define O_CDF  0
#define O_ZSG  0
#define O_RGB  512
#define O_HU   336
#define O_HM   468
#define O_ZF   1024
#define O_AB   1152
#define O_BIAS 1216

typedef __fp16 h16x2 __attribute__((ext_vector_type(2)));
typedef _Float16 f16x8 __attribute__((ext_vector_type(8)));
typedef float f32x4 __attribute__((ext_vector_type(4)));

// ws float layout: [0..255] B-fragment (64 lanes x 4 dwords of f16 pairs)
//                  [256..259] bfused[c]   [260] b2_0
#define WS_FRAG 0
#define WS_BF   256
#define WS_B20  260

__device__ __forceinline__ h16x2 pk_fma_f16(h16x2 a, h16x2 b, h16x2 c) {
    h16x2 d;
    asm("v_pk_fma_f16 %0, %1, %2, %3" : "=v"(d) : "v"(a), "v"(b), "v"(c));
    return d;
}
__device__ __forceinline__ h16x2 pk_relu_f16(h16x2 a) {
    h16x2 d;
    asm("v_pk_max_f16 %0, %1, 0" : "=v"(d) : "v"(a));
    return d;
}
__device__ __forceinline__ float softplus_f(float x) {
    float e = __builtin_amdgcn_exp2f(x * 1.442695041f);
    return 0.69314718056f * __builtin_amdgcn_logf(1.0f + e);
}
__device__ __forceinline__ float sigmoid_f(float x) {
    float e = __builtin_amdgcn_exp2f(x * -1.442695041f);
    return __builtin_amdgcn_rcpf(1.0f + e);
}
__device__ __forceinline__ float clampf(float x, float lo, float hi) {
    return fminf(fmaxf(x, lo), hi);
}
__device__ __forceinline__ uint2 pack_rgb(float c0, float c1, float c2, float c3) {
    h16x2 p0 = __builtin_amdgcn_cvt_pkrtz(c0, c1);
    h16x2 p1 = __builtin_amdgcn_cvt_pkrtz(c2, c3);
    uint2 r;
    r.x = __builtin_bit_cast(unsigned int, p0);
    r.y = __builtin_bit_cast(unsigned int, p1);
    return r;
}
__device__ __forceinline__ void unpack_rgb(unsigned int lo, unsigned int hi, float* c) {
    h16x2 p0 = __builtin_bit_cast(h16x2, lo);
    h16x2 p1 = __builtin_bit_cast(h16x2, hi);
    c[0] = (float)p0.x; c[1] = (float)p0.y; c[2] = (float)p1.x; c[3] = (float)p1.y;
}

// ---- DPP wave64 inclusive scans ----
template<int CTRL, int RMASK>
__device__ __forceinline__ float dppf(float old, float v) {
    int r = __builtin_amdgcn_update_dpp(__builtin_bit_cast(int, old),
                                        __builtin_bit_cast(int, v),
                                        CTRL, RMASK, 0xf, false);
    return __builtin_bit_cast(float, r);
}
template<int CTRL, int RMASK>
__device__ __forceinline__ int dppi(int old, int v) {
    return __builtin_amdgcn_update_dpp(old, v, CTRL, RMASK, 0xf, false);
}
__device__ __forceinline__ float scan_mul_f(float v) {
    v *= dppf<0x111, 0xf>(1.0f, v);
    v *= dppf<0x112, 0xf>(1.0f, v);
    v *= dppf<0x114, 0xf>(1.0f, v);
    v *= dppf<0x118, 0xf>(1.0f, v);
    v *= dppf<0x142, 0xa>(1.0f, v);
    v *= dppf<0x143, 0xc>(1.0f, v);
    return v;
}
__device__ __forceinline__ float scan_add_f(float v) {
    v += dppf<0x111, 0xf>(0.0f, v);
    v += dppf<0x112, 0xf>(0.0f, v);
    v += dppf<0x114, 0xf>(0.0f, v);
    v += dppf<0x118, 0xf>(0.0f, v);
    v += dppf<0x142, 0xa>(0.0f, v);
    v += dppf<0x143, 0xc>(0.0f, v);
    return v;
}
__device__ __forceinline__ int scan_add_i(int v) {
    v += dppi<0x111, 0xf>(0, v);
    v += dppi<0x112, 0xf>(0, v);
    v += dppi<0x114, 0xf>(0, v);
    v += dppi<0x118, 0xf>(0, v);
    v += dppi<0x142, 0xa>(0, v);
    v += dppi<0x143, 0xc>(0, v);
    return v;
}

// B-fragment prep (unchanged, proven)
extern "C" __global__ __launch_bounds__(64)
void nerf_prep_kernel(const float* __restrict__ W2, const float* __restrict__ b2,
                      const float* __restrict__ Wc, const float* __restrict__ bc,
                      float* __restrict__ ws) {
    const int t = threadIdx.x;
    const int col = t & 15, kb = t >> 4;
    float v[8];
#pragma unroll
    for (int j = 0; j < 8; ++j) {
        const int k = kb * 8 + j;
        float x = 0.0f;
        if (col == 0) {
            x = W2[k * 16];
        } else if (col <= 4) {
#pragma unroll
            for (int f = 0; f < FEAT; ++f) x += W2[k * 16 + 1 + f] * Wc[f * 4 + (col - 1)];
        }
        v[j] = x;
    }
#pragma unroll
    for (int m = 0; m < 4; ++m) {
        h16x2 p = __builtin_amdgcn_cvt_pkrtz(v[2 * m], v[2 * m + 1]);
        ws[WS_FRAG + t * 4 + m] = __builtin_bit_cast(float, p);
    }
    if (t < 4) {
        float b = bc[t];
#pragma unroll
        for (int f = 0; f < FEAT; ++f) b += b2[1 + f] * Wc[f * 4 + t];
        ws[WS_BF + t] = b;
    }
    if (t == 0) ws[WS_B20] = b2[0];
}

struct CoarseTag { static constexpr bool fine = false; };
struct FineTag   { static constexpr bool fine = true;  };

extern "C" __global__ __launch_bounds__(256, 6)
void nerf_render_kernel(const float* __restrict__ rays_o,
                        const float* __restrict__ rays_d,
                        const float* __restrict__ W1, const float* __restrict__ b1,
                        const float* __restrict__ Wd,
                        const float* __restrict__ wsf,
                        float* __restrict__ out) {
    const int wv   = threadIdx.x >> 6;
    const int lane = threadIdx.x & 63;
    const int ray  = blockIdx.x * RPB + wv;
    const int col16 = lane & 15;        // output col (C layout)
    const int kb    = lane >> 4;        // C row-group

    __shared__ __align__(16) float smem[RPB][PRW];
    float*     base  = &smem[wv][0];
    unsigned*  sStgU = (unsigned*)(base + O_STG);
    uint2*     sRgb  = (uint2*)(base + O_RGB);
    float4*    sAB   = (float4*)(base + O_AB);
    float*     sBias = base + O_BIAS;
    float*     sCdf  = base + O_CDF;
    float*     sZf   = base + O_ZF;
    int*       sHU   = (int*)(base + O_HU);
    int*       sHM   = (int*)(base + O_HM);

    // ---- ray setup (uniform per wave) ----
    const float ox = rays_o[ray * 3 + 0], oy = rays_o[ray * 3 + 1], oz = rays_o[ray * 3 + 2];
    const float dx = rays_d[ray * 3 + 0], dy = rays_d[ray * 3 + 1], dz = rays_d[ray * 3 + 2];

    auto invd = [](float d) { float dd = (fabsf(d) < 1e-9f) ? 1e-9f : d; return 1.0f / dd; };
    const float ixv = invd(dx), iyv = invd(dy), izv = invd(dz);
    const float t1x = (-BOUNDF - ox) * ixv, t2x = (BOUNDF - ox) * ixv;
    const float t1y = (-BOUNDF - oy) * iyv, t2y = (BOUNDF - oy) * iyv;
    const float t1z = (-BOUNDF - oz) * izv, t2z = (BOUNDF - oz) * izv;
    float nearv = fmaxf(fmaxf(fminf(t1x, t2x), fminf(t1y, t2y)), fminf(t1z, t2z));
    nearv = fmaxf(nearv, MIN_NEAR);
    float farv = fminf(fminf(fmaxf(t1x, t2x), fmaxf(t1y, t2y)), fmaxf(t1z, t2z));
    farv = fmaxf(farv, nearv + 1e-5f);
    const float fmn = farv - nearv;
    const float sample_dist = fmn * (1.0f / (float)S);
    const float dstep = fmn * (1.0f / 127.0f);

    // zero histograms (int4: 2 DS ops); entries 0..128 each (pad covered)
    {
        int4 z4i; z4i.x = 0; z4i.y = 0; z4i.z = 0; z4i.w = 0;
        if (lane < 33) {
            *(int4*)(sHU + 4 * lane) = z4i;    // covers 0..131
            *(int4*)(sHM + 4 * lane) = z4i;    // covers 0..131
        }
    }

    // layer-1 fold: A_j = b1_j + o.W1_j ; B_j = d.W1_j (interleaved pairs)
    if (lane < 32) {
        const int j = lane;
        const float w0 = W1[j], w1 = W1[32 + j], w2 = W1[64 + j];
        ((float*)&sAB[j >> 1])[(j & 1)]     = b1[j] + ox * w0 + oy * w1 + oz * w2;
        ((float*)&sAB[j >> 1])[2 + (j & 1)] = dx * w0 + dy * w1 + dz * w2;
    }
    // acc-init bias per output col
    if (lane < 16) {
        float b = 0.0f;
        if (lane == 0) b = wsf[WS_B20];
        else if (lane <= 4) {
            const int c = lane - 1;
            b = wsf[WS_BF + c] + dx * Wd[c] + dy * Wd[4 + c] + dz * Wd[8 + c];
        }
        sBias[lane] = b;
    }
    __builtin_amdgcn_wave_barrier();

    // ---- per-lane fragments ----
    h16x2 Af[4], Bf[4];
#pragma unroll
    for (int m = 0; m < 4; ++m) {
        const float4 ab = sAB[kb * 4 + m];
        Af[m] = __builtin_amdgcn_cvt_pkrtz(ab.x, ab.y);
        Bf[m] = __builtin_amdgcn_cvt_pkrtz(ab.z, ab.w);
    }
    const float4 frw = ((const float4*)wsf)[lane];      // B-frag (16B/lane)
    const f16x8 bfrag = __builtin_bit_cast(f16x8, frw);
    const float bv = sBias[col16];
    f32x4 accB; accB[0] = bv; accB[1] = bv; accB[2] = bv; accB[3] = bv;

    // ---- MFMA MLP pass: 8 tiles of 16 samples; staging packed f16 ----
    auto mfma_pass = [&](auto tag) {
#pragma unroll
        for (int t = 0; t < 8; ++t) {
            float zs;
            if constexpr (decltype(tag)::fine) zs = sZf[t * 16 + col16];
            else                               zs = fmaf((float)(t * 16 + col16), dstep, nearv);
            const h16x2 z2 = __builtin_amdgcn_cvt_pkrtz(zs, zs);
            h16x2 h0 = pk_relu_f16(pk_fma_f16(Bf[0], z2, Af[0]));
            h16x2 h1 = pk_relu_f16(pk_fma_f16(Bf[1], z2, Af[1]));
            h16x2 h2 = pk_relu_f16(pk_fma_f16(Bf[2], z2, Af[2]));
            h16x2 h3 = pk_relu_f16(pk_fma_f16(Bf[3], z2, Af[3]));
            uint4 au;
            au.x = __builtin_bit_cast(unsigned int, h0);
            au.y = __builtin_bit_cast(unsigned int, h1);
            au.z = __builtin_bit_cast(unsigned int, h2);
            au.w = __builtin_bit_cast(unsigned int, h3);
            const f16x8 afrag = __builtin_bit_cast(f16x8, au);
            f32x4 acc = __builtin_amdgcn_mfma_f32_16x16x32_f16(afrag, bfrag, accB, 0, 0, 0);
            if (col16 < 5) {
                uint2 p;
                p.x = __builtin_bit_cast(unsigned int, __builtin_amdgcn_cvt_pkrtz(acc[0], acc[1]));
                p.y = __builtin_bit_cast(unsigned int, __builtin_amdgcn_cvt_pkrtz(acc[2], acc[3]));
                *(uint2*)&sStgU[col16 * 66 + t * 8 + kb * 2] = p;
            }
        }
    };
    // readback: 2 samples (2*lane, 2*lane+1) via 5 x ds_read_b32 (f16 pairs)
    auto readback = [&](float* sg, uint2* rgb) {
        unsigned u[5];
#pragma unroll
        for (int c = 0; c < 5; ++c) u[c] = sStgU[c * 66 + lane];
        float a[5], b[5];
#pragma unroll
        for (int c = 0; c < 5; ++c) {
            h16x2 p = __builtin_bit_cast(h16x2, u[c]);
            a[c] = (float)p.x; b[c] = (float)p.y;
        }
        sg[0] = softplus_f(a[0]);
        sg[1] = softplus_f(b[0]);
        rgb[0] = pack_rgb(sigmoid_f(a[1]), sigmoid_f(a[2]), sigmoid_f(a[3]), sigmoid_f(a[4]));
        rgb[1] = pack_rgb(sigmoid_f(b[1]), sigmoid_f(b[2]), sigmoid_f(b[3]), sigmoid_f(b[4]));
    };

    // ---- coarse pass ----
    mfma_pass(CoarseTag{});
    __builtin_amdgcn_wave_barrier();
    float sgc[2]; uint2 rgc[2];
    readback(sgc, rgc);
    const float zc0 = fmaf((float)(2 * lane), dstep, nearv);
    const float zc1 = zc0 + dstep;
    __builtin_amdgcn_wave_barrier();    // stage consumed; cdf may overwrite

    // ---- coarse composite weights (for PDF) ----
    const float dc1 = (lane == 63) ? sample_dist : dstep;
    const float ec0 = __builtin_amdgcn_exp2f(dstep * sgc[0] * -1.442695041f);
    const float ec1 = __builtin_amdgcn_exp2f(dc1 * sgc[1] * -1.442695041f);
    const float alc0 = 1.f - ec0, alc1 = 1.f - ec1;
    const float vc0 = ec0 + 1e-15f, vc1 = ec1 + 1e-15f;
    const float incl = scan_mul_f(vc0 * vc1);
    float excl = __shfl_up(incl, 1, 64);
    if (lane == 0) excl = 1.f;
    const float wc0 = alc0 * excl;
    const float wc1 = alc1 * (excl * vc0);

    const float wnext = __shfl_down(wc0, 1, 64);      // w(2l+2)
    float p0 = wc1 + 1e-5f, p1 = wnext + 1e-5f;
    if (lane == 63) { p0 = 0.f; p1 = 0.f; }
    const float s01 = p0 + p1;
    const float cinc = scan_add_f(s01);
    const float total = __builtin_bit_cast(float,
        __builtin_amdgcn_readlane(__builtin_bit_cast(int, cinc), 63));
    const float rtot = __builtin_amdgcn_rcpf(total);
    const float cexcl = cinc - s01;
    if (lane < 63) {
        const float cdfA = (cexcl + p0) * rtot;
        const float cdfB = (cexcl + p0 + p1) * rtot;
        sCdf[2 * lane + 1] = cdfA;
        sCdf[2 * lane + 2] = cdfB;
        int cA = (int)ceilf(fmaf(128.f, cdfA, -0.5f));
        int cB = (int)ceilf(fmaf(128.f, cdfB, -0.5f));
        cA = min(max(cA, 0), 128); cB = min(max(cB, 0), 128);
        atomicAdd(&sHU[cA], 1);
        atomicAdd(&sHU[cB], 1);
    } else {
        sCdf[0] = 0.f;
        atomicAdd(&sHU[0], 1);
    }
    __builtin_amdgcn_wave_barrier();

    // ---- inds via histogram prefix; closed-form bin midpoints ----
    const int2 hu = *(const int2*)(sHU + 2 * lane);
    const int hs = hu.x + hu.y;
    const int hscan = scan_add_i(hs);
    const int hexcl = hscan - hs;
    const int indsA = hexcl + hu.x;
    const int indsB = hexcl + hs;

    auto lerp_z = [&](int inds, float u) -> float {
        const int below = inds - 1;
        const int above = min(inds, 126);
        const float cb = sCdf[below], ca = sCdf[above];
        const float bb = fmaf((float)below + 0.5f, dstep, nearv);
        const float ba = fmaf((float)above + 0.5f, dstep, nearv);
        float den = ca - cb;
        if (den < 1e-5f) den = 1.0f;
        const float t = (u - cb) * __builtin_amdgcn_rcpf(den);
        return bb + t * (ba - bb);
    };
    const float zf0 = lerp_z(indsA, ((float)(2 * lane) + 0.5f) * (1.0f / 128.f));
    const float zf1 = lerp_z(indsB, ((float)(2 * lane) + 1.5f) * (1.0f / 128.f));
    sZf[2 * lane]     = zf0;
    sZf[2 * lane + 1] = zf1;

    // rank of fine in coarse (closed form) + histogram
    const float inv_stepz = 127.0f / fmn;
    int r0 = (int)floorf((zf0 - nearv) * inv_stepz) + 1;
    int r1 = (int)floorf((zf1 - nearv) * inv_stepz) + 1;
    r0 = min(max(r0, 0), 128); r1 = min(max(r1, 0), 128);
    atomicAdd(&sHM[r0], 1);
    atomicAdd(&sHM[r1], 1);
    __builtin_amdgcn_wave_barrier();    // cdf consumed; fine stage may overwrite

    // ---- fine pass ----
    mfma_pass(FineTag{});
    __builtin_amdgcn_wave_barrier();
    float sgf[2]; uint2 rgf[2];
    readback(sgf, rgf);
    __builtin_amdgcn_wave_barrier();    // stage consumed before sorted writes

    // ---- merge ranks via histogram prefix; scatter sorted triples ----
    const int2 hm = *(const int2*)(sHM + 2 * lane);   // read precedes writes below
    const int ms = hm.x + hm.y;
    const int mscan = scan_add_i(ms);
    const int mexcl = mscan - ms;
    const int dC0 = 2 * lane + (mexcl + hm.x);
    const int dC1 = 2 * lane + 1 + (mexcl + ms);
    const int dF0 = 2 * lane + r0;
    const int dF1 = 2 * lane + 1 + r1;

    auto il = [](int d) { return ((d & 3) << 6) + (d >> 2); };
    {
        const int a0 = il(dC0), a1 = il(dC1), a2 = il(dF0), a3 = il(dF1);
        float2 v0; v0.x = zc0; v0.y = sgc[0];
        float2 v1; v1.x = zc1; v1.y = sgc[1];
        float2 v2; v2.x = zf0; v2.y = sgf[0];
        float2 v3; v3.x = zf1; v3.y = sgf[1];
        *(float2*)&base[O_ZSG + 2 * a0] = v0;  sRgb[a0] = rgc[0];
        *(float2*)&base[O_ZSG + 2 * a1] = v1;  sRgb[a1] = rgc[1];
        *(float2*)&base[O_ZSG + 2 * a2] = v2;  sRgb[a2] = rgf[0];
        *(float2*)&base[O_ZSG + 2 * a3] = v3;  sRgb[a3] = rgf[1];
    }
    __builtin_amdgcn_wave_barrier();

    // ---- final compositing: 4 sorted samples per lane (packed b64 reads) ----
    float z_[4], g_[4]; uint2 q_[4];
#pragma unroll
    for (int row = 0; row < 4; ++row) {
        const float2 zg = *(const float2*)&base[O_ZSG + 2 * (row * 64 + lane)];
        z_[row] = zg.x; g_[row] = zg.y;
        q_[row] = sRgb[row * 64 + lane];
    }

    const float znx = __shfl_down(z_[0], 1, 64);
    const float dd0 = z_[1] - z_[0];
    const float dd1 = z_[2] - z_[1];
    const float dd2 = z_[3] - z_[2];
    const float dd3 = (lane == 63) ? sample_dist : (znx - z_[3]);

    const float e0 = __builtin_amdgcn_exp2f(dd0 * g_[0] * -1.442695041f);
    const float e1 = __builtin_amdgcn_exp2f(dd1 * g_[1] * -1.442695041f);
    const float e2 = __builtin_amdgcn_exp2f(dd2 * g_[2] * -1.442695041f);
    const float e3 = __builtin_amdgcn_exp2f(dd3 * g_[3] * -1.442695041f);
    const float al0 = 1.f - e0, al1 = 1.f - e1, al2 = 1.f - e2, al3 = 1.f - e3;
    const float v0 = e0 + 1e-15f, v1 = e1 + 1e-15f, v2 = e2 + 1e-15f, v3 = e3 + 1e-15f;

    const float incl2 = scan_mul_f(v0 * v1 * v2 * v3);
    float T0 = __shfl_up(incl2, 1, 64);
    if (lane == 0) T0 = 1.f;
    const float T1 = T0 * v0, T2 = T1 * v1, T3 = T2 * v2;
    const float w0 = al0 * T0, w1 = al1 * T1, w2 = al2 * T2, w3 = al3 * T3;

    const float inv_fn = 1.0f / fmn;
    const float oz0 = clampf((z_[0] - nearv) * inv_fn, 0.f, 1.f);
    const float oz1 = clampf((z_[1] - nearv) * inv_fn, 0.f, 1.f);
    const float oz2 = clampf((z_[2] - nearv) * inv_fn, 0.f, 1.f);
    const float oz3 = clampf((z_[3] - nearv) * inv_fn, 0.f, 1.f);

    float r0c[4], r1c[4], r2c[4], r3c[4];
    unpack_rgb(q_[0].x, q_[0].y, r0c);
    unpack_rgb(q_[1].x, q_[1].y, r1c);
    unpack_rgb(q_[2].x, q_[2].y, r2c);
    unpack_rgb(q_[3].x, q_[3].y, r3c);

    float vals[6];
#pragma unroll
    for (int c = 0; c < 4; ++c)
        vals[c] = w0 * r0c[c] + w1 * r1c[c] + w2 * r2c[c] + w3 * r3c[c];
    vals[4] = w0 * oz0 + w1 * oz1 + w2 * oz2 + w3 * oz3;
    vals[5] = w0 + w1 + w2 + w3;

#pragma unroll
    for (int q = 0; q < 6; ++q) vals[q] = scan_add_f(vals[q]);

    if (lane == 63) {
        const float wsum = vals[5];
#pragma unroll
        for (int c = 0; c < 4; ++c)
            out[ray * 4 + c] = vals[c] + (1.0f - wsum);
        out[4 * N_RAYS + ray] = vals[4];
        out[5 * N_RAYS + ray] = wsum;
    }
}

extern "C" void kernel_launch(void* const* d_in, const int* in_sizes, int n_in,
                              void* d_out, int out_size, void* d_ws, size_t ws_size,
                              hipStream_t stream) {
    const float* rays_o = (const float*)d_in[0];
    const float* rays_d = (const float*)d_in[1];
    const float* W1 = (const float*)d_in[2];
    const float* b1 = (const float*)d_in[3];
    const float* W2 = (const float*)d_in[4];
    const float* b2 = (const float*)d_in[5];
    const float* Wc = (const float*)d_in[6];
    const float* Wd = (const float*)d_in[7];
    const float* bc = (const float*)d_in[8];
    float* out = (float*)d_out;
    float* ws  = (float*)d_ws;

    hipLaunchKernelGGL(nerf_prep_kernel, dim3(1), dim3(64), 0, stream,
                       W2, b2, Wc, bc, ws);
    hipLaunchKernelGGL(nerf_render_kernel, dim3(N_RAYS / RPB), dim3(256), 0, stream,
                       rays_o, rays_d, W1, b1, Wd, ws, out);
}

// Round 13
// 33.650 us; speedup vs baseline: 1.0346x; 1.0346x over previous
//
#include <hip/hip_runtime.h>
#include <math.h>

#define N_RAYS 16384
#define S 128
#define FEAT 15
#define BOUNDF 2.0f
#define MIN_NEAR 0.05f
#define RPB 4              // rays (waves) per 256-thread block
#define PRW 1232           // per-ray LDS words (4928 B)

// per-ray LDS word offsets — aliasing sequenced by single-wave in-order DS ops
// (structure identical to R10, the best-measured configuration):
//   stage 0..659 live per MLP pass; cdf 0..127 written after coarse readback,
//   consumed before fine pass rewrites stage; HU/HM 660..920 consumed before
//   sorted scatter writes 0..1023; zf/AB/bias 1024..1231 un-aliased.
#define O_STG  0
#define O_CDF  0
#define O_ZS   0
#define O_SIG  256
#define O_RGB  512
#define O_HU   660
#define O_HM   792
#define O_ZF   1024
#define O_AB   1152
#define O_BIAS 1216

typedef __fp16 h16x2 __attribute__((ext_vector_type(2)));
typedef _Float16 f16x8 __attribute__((ext_vector_type(8)));
typedef float f32x4 __attribute__((ext_vector_type(4)));

// ws float layout: [0..255] B-fragment (64 lanes x 4 dwords of f16 pairs)
//                  [256..259] bfused[c]   [260] b2_0
#define WS_FRAG 0
#define WS_BF   256
#define WS_B20  260

__device__ __forceinline__ h16x2 pk_fma_f16(h16x2 a, h16x2 b, h16x2 c) {
    h16x2 d;
    asm("v_pk_fma_f16 %0, %1, %2, %3" : "=v"(d) : "v"(a), "v"(b), "v"(c));
    return d;
}
__device__ __forceinline__ h16x2 pk_relu_f16(h16x2 a) {
    h16x2 d;
    asm("v_pk_max_f16 %0, %1, 0" : "=v"(d) : "v"(a));
    return d;
}
__device__ __forceinline__ float softplus_f(float x) {
    float e = __builtin_amdgcn_exp2f(x * 1.442695041f);
    return 0.69314718056f * __builtin_amdgcn_logf(1.0f + e);
}
__device__ __forceinline__ float sigmoid_f(float x) {
    float e = __builtin_amdgcn_exp2f(x * -1.442695041f);
    return __builtin_amdgcn_rcpf(1.0f + e);
}
__device__ __forceinline__ float clampf(float x, float lo, float hi) {
    return fminf(fmaxf(x, lo), hi);
}
__device__ __forceinline__ uint2 pack_rgb(float c0, float c1, float c2, float c3) {
    h16x2 p0 = __builtin_amdgcn_cvt_pkrtz(c0, c1);
    h16x2 p1 = __builtin_amdgcn_cvt_pkrtz(c2, c3);
    uint2 r;
    r.x = __builtin_bit_cast(unsigned int, p0);
    r.y = __builtin_bit_cast(unsigned int, p1);
    return r;
}
__device__ __forceinline__ void unpack_rgb(unsigned int lo, unsigned int hi, float* c) {
    h16x2 p0 = __builtin_bit_cast(h16x2, lo);
    h16x2 p1 = __builtin_bit_cast(h16x2, hi);
    c[0] = (float)p0.x; c[1] = (float)p0.y; c[2] = (float)p1.x; c[3] = (float)p1.y;
}

// ---- DPP wave64 inclusive scans ----
template<int CTRL, int RMASK>
__device__ __forceinline__ float dppf(float old, float v) {
    int r = __builtin_amdgcn_update_dpp(__builtin_bit_cast(int, old),
                                        __builtin_bit_cast(int, v),
                                        CTRL, RMASK, 0xf, false);
    return __builtin_bit_cast(float, r);
}
template<int CTRL, int RMASK>
__device__ __forceinline__ int dppi(int old, int v) {
    return __builtin_amdgcn_update_dpp(old, v, CTRL, RMASK, 0xf, false);
}
__device__ __forceinline__ float scan_mul_f(float v) {
    v *= dppf<0x111, 0xf>(1.0f, v);
    v *= dppf<0x112, 0xf>(1.0f, v);
    v *= dppf<0x114, 0xf>(1.0f, v);
    v *= dppf<0x118, 0xf>(1.0f, v);
    v *= dppf<0x142, 0xa>(1.0f, v);
    v *= dppf<0x143, 0xc>(1.0f, v);
    return v;
}
__device__ __forceinline__ float scan_add_f(float v) {
    v += dppf<0x111, 0xf>(0.0f, v);
    v += dppf<0x112, 0xf>(0.0f, v);
    v += dppf<0x114, 0xf>(0.0f, v);
    v += dppf<0x118, 0xf>(0.0f, v);
    v += dppf<0x142, 0xa>(0.0f, v);
    v += dppf<0x143, 0xc>(0.0f, v);
    return v;
}
__device__ __forceinline__ int scan_add_i(int v) {
    v += dppi<0x111, 0xf>(0, v);
    v += dppi<0x112, 0xf>(0, v);
    v += dppi<0x114, 0xf>(0, v);
    v += dppi<0x118, 0xf>(0, v);
    v += dppi<0x142, 0xa>(0, v);
    v += dppi<0x143, 0xc>(0, v);
    return v;
}

// B-fragment prep (unchanged, proven)
extern "C" __global__ __launch_bounds__(64)
void nerf_prep_kernel(const float* __restrict__ W2, const float* __restrict__ b2,
                      const float* __restrict__ Wc, const float* __restrict__ bc,
                      float* __restrict__ ws) {
    const int t = threadIdx.x;
    const int col = t & 15, kb = t >> 4;
    float v[8];
#pragma unroll
    for (int j = 0; j < 8; ++j) {
        const int k = kb * 8 + j;
        float x = 0.0f;
        if (col == 0) {
            x = W2[k * 16];
        } else if (col <= 4) {
#pragma unroll
            for (int f = 0; f < FEAT; ++f) x += W2[k * 16 + 1 + f] * Wc[f * 4 + (col - 1)];
        }
        v[j] = x;
    }
#pragma unroll
    for (int m = 0; m < 4; ++m) {
        h16x2 p = __builtin_amdgcn_cvt_pkrtz(v[2 * m], v[2 * m + 1]);
        ws[WS_FRAG + t * 4 + m] = __builtin_bit_cast(float, p);
    }
    if (t < 4) {
        float b = bc[t];
#pragma unroll
        for (int f = 0; f < FEAT; ++f) b += b2[1 + f] * Wc[f * 4 + t];
        ws[WS_BF + t] = b;
    }
    if (t == 0) ws[WS_B20] = b2[0];
}

struct CoarseTag { static constexpr bool fine = false; };
struct FineTag   { static constexpr bool fine = true;  };

extern "C" __global__ __launch_bounds__(256, 8)
void nerf_render_kernel(const float* __restrict__ rays_o,
                        const float* __restrict__ rays_d,
                        const float* __restrict__ W1, const float* __restrict__ b1,
                        const float* __restrict__ Wd,
                        const float* __restrict__ wsf,
                        float* __restrict__ out) {
    const int wv   = threadIdx.x >> 6;
    const int lane = threadIdx.x & 63;
    const int ray  = blockIdx.x * RPB + wv;
    const int col16 = lane & 15;        // output col (C layout)
    const int kb    = lane >> 4;        // C row-group

    __shared__ __align__(16) float smem[RPB][PRW];
    float*  base  = &smem[wv][0];
    float*  sStg  = base + O_STG;
    float*  sZs   = base + O_ZS;
    float*  sSig  = base + O_SIG;
    uint2*  sRgb  = (uint2*)(base + O_RGB);
    float4* sAB   = (float4*)(base + O_AB);
    float*  sBias = base + O_BIAS;
    float*  sCdf  = base + O_CDF;
    float*  sZf   = base + O_ZF;
    int*    sHU   = (int*)(base + O_HU);
    int*    sHM   = (int*)(base + O_HM);

    // ---- ray setup (uniform per wave) ----
    const float ox = rays_o[ray * 3 + 0], oy = rays_o[ray * 3 + 1], oz = rays_o[ray * 3 + 2];
    const float dx = rays_d[ray * 3 + 0], dy = rays_d[ray * 3 + 1], dz = rays_d[ray * 3 + 2];

    auto invd = [](float d) { float dd = (fabsf(d) < 1e-9f) ? 1e-9f : d; return 1.0f / dd; };
    const float ixv = invd(dx), iyv = invd(dy), izv = invd(dz);
    const float t1x = (-BOUNDF - ox) * ixv, t2x = (BOUNDF - ox) * ixv;
    const float t1y = (-BOUNDF - oy) * iyv, t2y = (BOUNDF - oy) * iyv;
    const float t1z = (-BOUNDF - oz) * izv, t2z = (BOUNDF - oz) * izv;
    float nearv = fmaxf(fmaxf(fminf(t1x, t2x), fminf(t1y, t2y)), fminf(t1z, t2z));
    nearv = fmaxf(nearv, MIN_NEAR);
    float farv = fminf(fminf(fmaxf(t1x, t2x), fmaxf(t1y, t2y)), fmaxf(t1z, t2z));
    farv = fmaxf(farv, nearv + 1e-5f);
    const float fmn = farv - nearv;
    const float sample_dist = fmn * (1.0f / (float)S);
    const float dstep = fmn * (1.0f / 127.0f);

    // zero histograms
    sHU[lane] = 0; sHU[64 + lane] = 0;
    sHM[lane] = 0; sHM[64 + lane] = 0;
    if (lane == 0) { sHU[128] = 0; sHM[128] = 0; }

    // layer-1 fold: A_j = b1_j + o.W1_j ; B_j = d.W1_j (interleaved pairs)
    if (lane < 32) {
        const int j = lane;
        const float w0 = W1[j], w1 = W1[32 + j], w2 = W1[64 + j];
        ((float*)&sAB[j >> 1])[(j & 1)]     = b1[j] + ox * w0 + oy * w1 + oz * w2;
        ((float*)&sAB[j >> 1])[2 + (j & 1)] = dx * w0 + dy * w1 + dz * w2;
    }
    // acc-init bias per output col
    if (lane < 16) {
        float b = 0.0f;
        if (lane == 0) b = wsf[WS_B20];
        else if (lane <= 4) {
            const int c = lane - 1;
            b = wsf[WS_BF + c] + dx * Wd[c] + dy * Wd[4 + c] + dz * Wd[8 + c];
        }
        sBias[lane] = b;
    }
    __builtin_amdgcn_wave_barrier();

    // ---- per-lane fragments ----
    h16x2 Af[4], Bf[4];
#pragma unroll
    for (int m = 0; m < 4; ++m) {
        const float4 ab = sAB[kb * 4 + m];
        Af[m] = __builtin_amdgcn_cvt_pkrtz(ab.x, ab.y);
        Bf[m] = __builtin_amdgcn_cvt_pkrtz(ab.z, ab.w);
    }
    const float4 frw = ((const float4*)wsf)[lane];      // B-frag (16B/lane)
    const f16x8 bfrag = __builtin_bit_cast(f16x8, frw);
    const float bv = sBias[col16];
    f32x4 accB; accB[0] = bv; accB[1] = bv; accB[2] = bv; accB[3] = bv;

    // ---- MFMA MLP pass: 8 tiles of 16 samples, K=32, f16 in / f32 out ----
    auto mfma_pass = [&](auto tag) {
#pragma unroll
        for (int t = 0; t < 8; ++t) {
            float zs;
            if constexpr (decltype(tag)::fine) zs = sZf[t * 16 + col16];
            else                               zs = fmaf((float)(t * 16 + col16), dstep, nearv);
            const h16x2 z2 = __builtin_amdgcn_cvt_pkrtz(zs, zs);
            h16x2 h0 = pk_relu_f16(pk_fma_f16(Bf[0], z2, Af[0]));
            h16x2 h1 = pk_relu_f16(pk_fma_f16(Bf[1], z2, Af[1]));
            h16x2 h2 = pk_relu_f16(pk_fma_f16(Bf[2], z2, Af[2]));
            h16x2 h3 = pk_relu_f16(pk_fma_f16(Bf[3], z2, Af[3]));
            uint4 au;
            au.x = __builtin_bit_cast(unsigned int, h0);
            au.y = __builtin_bit_cast(unsigned int, h1);
            au.z = __builtin_bit_cast(unsigned int, h2);
            au.w = __builtin_bit_cast(unsigned int, h3);
            const f16x8 afrag = __builtin_bit_cast(f16x8, au);
            f32x4 acc = __builtin_amdgcn_mfma_f32_16x16x32_f16(afrag, bfrag, accB, 0, 0, 0);
            if (col16 < 5) {
#pragma unroll
                for (int i = 0; i < 4; ++i)
                    sStg[col16 * 132 + t * 16 + kb * 4 + i] = acc[i];
            }
        }
    };
    auto readback = [&](int p, float& sg, uint2& rgb) {
        const float c0 = sStg[0 * 132 + p];
        const float c1 = sStg[1 * 132 + p];
        const float c2 = sStg[2 * 132 + p];
        const float c3 = sStg[3 * 132 + p];
        const float c4 = sStg[4 * 132 + p];
        sg  = softplus_f(c0);
        rgb = pack_rgb(sigmoid_f(c1), sigmoid_f(c2), sigmoid_f(c3), sigmoid_f(c4));
    };

    // ---- coarse pass ----
    mfma_pass(CoarseTag{});
    __builtin_amdgcn_wave_barrier();
    float sgc0, sgc1; uint2 rc0, rc1;
    readback(2 * lane,     sgc0, rc0);
    readback(2 * lane + 1, sgc1, rc1);
    const float zc0 = fmaf((float)(2 * lane), dstep, nearv);
    const float zc1 = zc0 + dstep;
    __builtin_amdgcn_wave_barrier();    // stage consumed; cdf may overwrite

    // ---- coarse composite weights (for PDF) ----
    const float dc1 = (lane == 63) ? sample_dist : dstep;
    const float ec0 = __builtin_amdgcn_exp2f(dstep * sgc0 * -1.442695041f);
    const float ec1 = __builtin_amdgcn_exp2f(dc1 * sgc1 * -1.442695041f);
    const float alc0 = 1.f - ec0, alc1 = 1.f - ec1;
    const float vc0 = ec0 + 1e-15f, vc1 = ec1 + 1e-15f;
    const float incl = scan_mul_f(vc0 * vc1);
    float excl = __shfl_up(incl, 1, 64);
    if (lane == 0) excl = 1.f;
    const float wc0 = alc0 * excl;
    const float wc1 = alc1 * (excl * vc0);

    const float wnext = __shfl_down(wc0, 1, 64);      // w(2l+2)
    float p0 = wc1 + 1e-5f, p1 = wnext + 1e-5f;
    if (lane == 63) { p0 = 0.f; p1 = 0.f; }
    const float s01 = p0 + p1;
    const float cinc = scan_add_f(s01);
    const float total = __builtin_bit_cast(float,
        __builtin_amdgcn_readlane(__builtin_bit_cast(int, cinc), 63));
    const float rtot = __builtin_amdgcn_rcpf(total);
    const float cexcl = cinc - s01;
    if (lane < 63) {
        const float cdfA = (cexcl + p0) * rtot;
        const float cdfB = (cexcl + p0 + p1) * rtot;
        sCdf[2 * lane + 1] = cdfA;
        sCdf[2 * lane + 2] = cdfB;
        int cA = (int)ceilf(fmaf(128.f, cdfA, -0.5f));
        int cB = (int)ceilf(fmaf(128.f, cdfB, -0.5f));
        cA = min(max(cA, 0), 128); cB = min(max(cB, 0), 128);
        atomicAdd(&sHU[cA], 1);
        atomicAdd(&sHU[cB], 1);
    } else {
        sCdf[0] = 0.f;
        atomicAdd(&sHU[0], 1);
    }
    __builtin_amdgcn_wave_barrier();

    // ---- inds via histogram prefix; closed-form bin midpoints ----
    const int2 hu = *(const int2*)(sHU + 2 * lane);
    const int hs = hu.x + hu.y;
    const int hscan = scan_add_i(hs);
    const int hexcl = hscan - hs;
    const int indsA = hexcl + hu.x;
    const int indsB = hexcl + hs;

    auto lerp_z = [&](int inds, float u) -> float {
        const int below = inds - 1;
        const int above = min(inds, 126);
        const float cb = sCdf[below], ca = sCdf[above];
        const float bb = fmaf((float)below + 0.5f, dstep, nearv);
        const float ba = fmaf((float)above + 0.5f, dstep, nearv);
        float den = ca - cb;
        if (den < 1e-5f) den = 1.0f;
        const float t = (u - cb) * __builtin_amdgcn_rcpf(den);
        return bb + t * (ba - bb);
    };
    const float zf0 = lerp_z(indsA, ((float)(2 * lane) + 0.5f) * (1.0f / 128.f));
    const float zf1 = lerp_z(indsB, ((float)(2 * lane) + 1.5f) * (1.0f / 128.f));
    sZf[2 * lane]     = zf0;
    sZf[2 * lane + 1] = zf1;

    // rank of fine in coarse (closed form) + histogram
    const float inv_stepz = 127.0f / fmn;
    int r0 = (int)floorf((zf0 - nearv) * inv_stepz) + 1;
    int r1 = (int)floorf((zf1 - nearv) * inv_stepz) + 1;
    r0 = min(max(r0, 0), 128); r1 = min(max(r1, 0), 128);
    atomicAdd(&sHM[r0], 1);
    atomicAdd(&sHM[r1], 1);
    __builtin_amdgcn_wave_barrier();    // cdf consumed; fine stage may overwrite

    // ---- fine pass ----
    mfma_pass(FineTag{});
    __builtin_amdgcn_wave_barrier();
    float sgf0, sgf1; uint2 rf0, rf1;
    readback(2 * lane,     sgf0, rf0);
    readback(2 * lane + 1, sgf1, rf1);
    __builtin_amdgcn_wave_barrier();    // stage consumed before sorted writes

    // ---- merge ranks via histogram prefix; scatter sorted triples ----
    const int2 hm = *(const int2*)(sHM + 2 * lane);   // read precedes writes below
    const int ms = hm.x + hm.y;
    const int mscan = scan_add_i(ms);
    const int mexcl = mscan - ms;
    const int dC0 = 2 * lane + (mexcl + hm.x);
    const int dC1 = 2 * lane + 1 + (mexcl + ms);
    const int dF0 = 2 * lane + r0;
    const int dF1 = 2 * lane + 1 + r1;

    auto il = [](int d) { return ((d & 3) << 6) + (d >> 2); };
    {
        const int a0 = il(dC0), a1 = il(dC1), a2 = il(dF0), a3 = il(dF1);
        sZs[a0] = zc0; sSig[a0] = sgc0; sRgb[a0] = rc0;
        sZs[a1] = zc1; sSig[a1] = sgc1; sRgb[a1] = rc1;
        sZs[a2] = zf0; sSig[a2] = sgf0; sRgb[a2] = rf0;
        sZs[a3] = zf1; sSig[a3] = sgf1; sRgb[a3] = rf1;
    }
    __builtin_amdgcn_wave_barrier();

    // ---- final compositing: 4 sorted samples per lane (il4 reads) ----
    const float z0 = sZs[lane],        z1 = sZs[64 + lane];
    const float z2 = sZs[128 + lane],  z3 = sZs[192 + lane];
    const float g0 = sSig[lane],       g1 = sSig[64 + lane];
    const float g2 = sSig[128 + lane], g3 = sSig[192 + lane];
    const uint2 q0 = sRgb[lane],       q1 = sRgb[64 + lane];
    const uint2 q2 = sRgb[128 + lane], q3 = sRgb[192 + lane];

    const float znx = __shfl_down(z0, 1, 64);
    const float dd0 = z1 - z0;
    const float dd1 = z2 - z1;
    const float dd2 = z3 - z2;
    const float dd3 = (lane == 63) ? sample_dist : (znx - z3);

    const float e0 = __builtin_amdgcn_exp2f(dd0 * g0 * -1.442695041f);
    const float e1 = __builtin_amdgcn_exp2f(dd1 * g1 * -1.442695041f);
    const float e2 = __builtin_amdgcn_exp2f(dd2 * g2 * -1.442695041f);
    const float e3 = __builtin_amdgcn_exp2f(dd3 * g3 * -1.442695041f);
    const float al0 = 1.f - e0, al1 = 1.f - e1, al2 = 1.f - e2, al3 = 1.f - e3;
    const float v0 = e0 + 1e-15f, v1 = e1 + 1e-15f, v2 = e2 + 1e-15f, v3 = e3 + 1e-15f;

    const float incl2 = scan_mul_f(v0 * v1 * v2 * v3);
    float T0 = __shfl_up(incl2, 1, 64);
    if (lane == 0) T0 = 1.f;
    const float T1 = T0 * v0, T2 = T1 * v1, T3 = T2 * v2;
    const float w0 = al0 * T0, w1 = al1 * T1, w2 = al2 * T2, w3 = al3 * T3;

    const float inv_fn = 1.0f / fmn;
    const float oz0 = clampf((z0 - nearv) * inv_fn, 0.f, 1.f);
    const float oz1 = clampf((z1 - nearv) * inv_fn, 0.f, 1.f);
    const float oz2 = clampf((z2 - nearv) * inv_fn, 0.f, 1.f);
    const float oz3 = clampf((z3 - nearv) * inv_fn, 0.f, 1.f);

    float r0c[4], r1c[4], r2c[4], r3c[4];
    unpack_rgb(q0.x, q0.y, r0c);
    unpack_rgb(q1.x, q1.y, r1c);
    unpack_rgb(q2.x, q2.y, r2c);
    unpack_rgb(q3.x, q3.y, r3c);

    float vals[6];
#pragma unroll
    for (int c = 0; c < 4; ++c)
        vals[c] = w0 * r0c[c] + w1 * r1c[c] + w2 * r2c[c] + w3 * r3c[c];
    vals[4] = w0 * oz0 + w1 * oz1 + w2 * oz2 + w3 * oz3;
    vals[5] = w0 + w1 + w2 + w3;

#pragma unroll
    for (int q = 0; q < 6; ++q) vals[q] = scan_add_f(vals[q]);

    if (lane == 63) {
        const float wsum = vals[5];
#pragma unroll
        for (int c = 0; c < 4; ++c)
            out[ray * 4 + c] = vals[c] + (1.0f - wsum);
        out[4 * N_RAYS + ray] = vals[4];
        out[5 * N_RAYS + ray] = wsum;
    }
}

extern "C" void kernel_launch(void* const* d_in, const int* in_sizes, int n_in,
                              void* d_out, int out_size, void* d_ws, size_t ws_size,
                              hipStream_t stream) {
    const float* rays_o = (const float*)d_in[0];
    const float* rays_d = (const float*)d_in[1];
    const float* W1 = (const float*)d_in[2];
    const float* b1 = (const float*)d_in[3];
    const float* W2 = (const float*)d_in[4];
    const float* b2 = (const float*)d_in[5];
    const float* Wc = (const float*)d_in[6];
    const float* Wd = (const float*)d_in[7];
    const float* bc = (const float*)d_in[8];
    float* out = (float*)d_out;
    float* ws  = (float*)d_ws;

    hipLaunchKernelGGL(nerf_prep_kernel, dim3(1), dim3(64), 0, stream,
                       W2, b2, Wc, bc, ws);
    hipLaunchKernelGGL(nerf_render_kernel, dim3(N_RAYS / RPB), dim3(256), 0, stream,
                       rays_o, rays_d, W1, b1, Wd, ws, out);
}

// Round 14
// 33.638 us; speedup vs baseline: 1.0349x; 1.0004x over previous
//
#include <hip/hip_runtime.h>
#include <math.h>

#define N_RAYS 16384
#define S 128
#define FEAT 15
#define BOUNDF 2.0f
#define MIN_NEAR 0.05f
#define RPB 4              // rays (waves) per 256-thread block
#define PRW 1232           // per-ray LDS words (4928 B)

// per-ray LDS word offsets — aliasing sequenced by single-wave in-order DS ops
// (structure identical to R10/R13, the best-measured configuration)
#define O_STG  0
#define O_CDF  0
#define O_ZS   0
#define O_SIG  256
#define O_RGB  512
#define O_HU   660
#define O_HM   792
#define O_ZF   1024
#define O_AB   1152
#define O_BIAS 1216

typedef __fp16 h16x2 __attribute__((ext_vector_type(2)));
typedef _Float16 f16x8 __attribute__((ext_vector_type(8)));
typedef float f32x4 __attribute__((ext_vector_type(4)));

__device__ __forceinline__ h16x2 pk_fma_f16(h16x2 a, h16x2 b, h16x2 c) {
    h16x2 d;
    asm("v_pk_fma_f16 %0, %1, %2, %3" : "=v"(d) : "v"(a), "v"(b), "v"(c));
    return d;
}
__device__ __forceinline__ h16x2 pk_relu_f16(h16x2 a) {
    h16x2 d;
    asm("v_pk_max_f16 %0, %1, 0" : "=v"(d) : "v"(a));
    return d;
}
__device__ __forceinline__ float softplus_f(float x) {
    float e = __builtin_amdgcn_exp2f(x * 1.442695041f);
    return 0.69314718056f * __builtin_amdgcn_logf(1.0f + e);
}
__device__ __forceinline__ float sigmoid_f(float x) {
    float e = __builtin_amdgcn_exp2f(x * -1.442695041f);
    return __builtin_amdgcn_rcpf(1.0f + e);
}
__device__ __forceinline__ float clampf(float x, float lo, float hi) {
    return fminf(fmaxf(x, lo), hi);
}
__device__ __forceinline__ uint2 pack_rgb(float c0, float c1, float c2, float c3) {
    h16x2 p0 = __builtin_amdgcn_cvt_pkrtz(c0, c1);
    h16x2 p1 = __builtin_amdgcn_cvt_pkrtz(c2, c3);
    uint2 r;
    r.x = __builtin_bit_cast(unsigned int, p0);
    r.y = __builtin_bit_cast(unsigned int, p1);
    return r;
}
__device__ __forceinline__ void unpack_rgb(unsigned int lo, unsigned int hi, float* c) {
    h16x2 p0 = __builtin_bit_cast(h16x2, lo);
    h16x2 p1 = __builtin_bit_cast(h16x2, hi);
    c[0] = (float)p0.x; c[1] = (float)p0.y; c[2] = (float)p1.x; c[3] = (float)p1.y;
}

// ---- DPP wave64 inclusive scans ----
template<int CTRL, int RMASK>
__device__ __forceinline__ float dppf(float old, float v) {
    int r = __builtin_amdgcn_update_dpp(__builtin_bit_cast(int, old),
                                        __builtin_bit_cast(int, v),
                                        CTRL, RMASK, 0xf, false);
    return __builtin_bit_cast(float, r);
}
template<int CTRL, int RMASK>
__device__ __forceinline__ int dppi(int old, int v) {
    return __builtin_amdgcn_update_dpp(old, v, CTRL, RMASK, 0xf, false);
}
__device__ __forceinline__ float scan_mul_f(float v) {
    v *= dppf<0x111, 0xf>(1.0f, v);
    v *= dppf<0x112, 0xf>(1.0f, v);
    v *= dppf<0x114, 0xf>(1.0f, v);
    v *= dppf<0x118, 0xf>(1.0f, v);
    v *= dppf<0x142, 0xa>(1.0f, v);
    v *= dppf<0x143, 0xc>(1.0f, v);
    return v;
}
__device__ __forceinline__ float scan_add_f(float v) {
    v += dppf<0x111, 0xf>(0.0f, v);
    v += dppf<0x112, 0xf>(0.0f, v);
    v += dppf<0x114, 0xf>(0.0f, v);
    v += dppf<0x118, 0xf>(0.0f, v);
    v += dppf<0x142, 0xa>(0.0f, v);
    v += dppf<0x143, 0xc>(0.0f, v);
    return v;
}
__device__ __forceinline__ int scan_add_i(int v) {
    v += dppi<0x111, 0xf>(0, v);
    v += dppi<0x112, 0xf>(0, v);
    v += dppi<0x114, 0xf>(0, v);
    v += dppi<0x118, 0xf>(0, v);
    v += dppi<0x142, 0xa>(0, v);
    v += dppi<0x143, 0xc>(0, v);
    return v;
}

struct CoarseTag { static constexpr bool fine = false; };
struct FineTag   { static constexpr bool fine = true;  };

extern "C" __global__ __launch_bounds__(256, 8)
void nerf_render_kernel(const float* __restrict__ rays_o,
                        const float* __restrict__ rays_d,
                        const float* __restrict__ W1, const float* __restrict__ b1,
                        const float* __restrict__ W2, const float* __restrict__ b2,
                        const float* __restrict__ Wc, const float* __restrict__ bc,
                        const float* __restrict__ Wd,
                        float* __restrict__ out) {
    const int wv   = threadIdx.x >> 6;
    const int lane = threadIdx.x & 63;
    const int ray  = blockIdx.x * RPB + wv;
    const int col16 = lane & 15;        // output col (C layout)
    const int kb    = lane >> 4;        // C row-group

    __shared__ __align__(16) float smem[RPB][PRW];
    __shared__ __align__(16) float sPrepF[256];   // block-shared B-fragment (f16 pairs)
    __shared__ float sPrepB[5];                   // bfused[0..3], b2_0
    float*  base  = &smem[wv][0];
    float*  sStg  = base + O_STG;
    float*  sZs   = base + O_ZS;
    float*  sSig  = base + O_SIG;
    uint2*  sRgb  = (uint2*)(base + O_RGB);
    float4* sAB   = (float4*)(base + O_AB);
    float*  sBias = base + O_BIAS;
    float*  sCdf  = base + O_CDF;
    float*  sZf   = base + O_ZF;
    int*    sHU   = (int*)(base + O_HU);
    int*    sHM   = (int*)(base + O_HM);

    // ---- block-cooperative prep: thread t computes one f16-pair dword of the
    //      MFMA B-fragment.  lane l = t>>2 holds B[(l>>4)*8+j][l&15] j=0..7;
    //      dword m = t&3 packs rows k0 = (l>>4)*8+2m, k0+1.
    {
        const int l = threadIdx.x >> 2, m = threadIdx.x & 3;
        const int c = l & 15, kbp = l >> 4;
        const int k0 = kbp * 8 + 2 * m;
        float v0 = 0.0f, v1 = 0.0f;
        if (c == 0) {
            v0 = W2[k0 * 16];
            v1 = W2[(k0 + 1) * 16];
        } else if (c <= 4) {
#pragma unroll
            for (int f = 0; f < FEAT; ++f) {
                const float wcf = Wc[f * 4 + (c - 1)];
                v0 = fmaf(W2[k0 * 16 + 1 + f], wcf, v0);
                v1 = fmaf(W2[(k0 + 1) * 16 + 1 + f], wcf, v1);
            }
        }
        h16x2 p = __builtin_amdgcn_cvt_pkrtz(v0, v1);
        sPrepF[threadIdx.x] = __builtin_bit_cast(float, p);
        if (threadIdx.x < 4) {
            float b = bc[threadIdx.x];
#pragma unroll
            for (int f = 0; f < FEAT; ++f)
                b = fmaf(b2[1 + f], Wc[f * 4 + threadIdx.x], b);
            sPrepB[threadIdx.x] = b;
        }
        if (threadIdx.x == 4) sPrepB[4] = b2[0];
    }

    // ---- ray setup (uniform per wave) ----
    const float ox = rays_o[ray * 3 + 0], oy = rays_o[ray * 3 + 1], oz = rays_o[ray * 3 + 2];
    const float dx = rays_d[ray * 3 + 0], dy = rays_d[ray * 3 + 1], dz = rays_d[ray * 3 + 2];

    auto invd = [](float d) { float dd = (fabsf(d) < 1e-9f) ? 1e-9f : d; return 1.0f / dd; };
    const float ixv = invd(dx), iyv = invd(dy), izv = invd(dz);
    const float t1x = (-BOUNDF - ox) * ixv, t2x = (BOUNDF - ox) * ixv;
    const float t1y = (-BOUNDF - oy) * iyv, t2y = (BOUNDF - oy) * iyv;
    const float t1z = (-BOUNDF - oz) * izv, t2z = (BOUNDF - oz) * izv;
    float nearv = fmaxf(fmaxf(fminf(t1x, t2x), fminf(t1y, t2y)), fminf(t1z, t2z));
    nearv = fmaxf(nearv, MIN_NEAR);
    float farv = fminf(fminf(fmaxf(t1x, t2x), fmaxf(t1y, t2y)), fmaxf(t1z, t2z));
    farv = fmaxf(farv, nearv + 1e-5f);
    const float fmn = farv - nearv;
    const float sample_dist = fmn * (1.0f / (float)S);
    const float dstep = fmn * (1.0f / 127.0f);

    // zero histograms
    sHU[lane] = 0; sHU[64 + lane] = 0;
    sHM[lane] = 0; sHM[64 + lane] = 0;
    if (lane == 0) { sHU[128] = 0; sHM[128] = 0; }

    // layer-1 fold: A_j = b1_j + o.W1_j ; B_j = d.W1_j (interleaved pairs)
    if (lane < 32) {
        const int j = lane;
        const float w0 = W1[j], w1 = W1[32 + j], w2 = W1[64 + j];
        ((float*)&sAB[j >> 1])[(j & 1)]     = b1[j] + ox * w0 + oy * w1 + oz * w2;
        ((float*)&sAB[j >> 1])[2 + (j & 1)] = dx * w0 + dy * w1 + dz * w2;
    }
    __syncthreads();   // prep + per-ray AB visible

    // acc-init bias per output col
    if (lane < 16) {
        float b = 0.0f;
        if (lane == 0) b = sPrepB[4];
        else if (lane <= 4) {
            const int c = lane - 1;
            b = sPrepB[c] + dx * Wd[c] + dy * Wd[4 + c] + dz * Wd[8 + c];
        }
        sBias[lane] = b;
    }
    __builtin_amdgcn_wave_barrier();

    // ---- per-lane fragments ----
    h16x2 Af[4], Bf[4];
#pragma unroll
    for (int m = 0; m < 4; ++m) {
        const float4 ab = sAB[kb * 4 + m];
        Af[m] = __builtin_amdgcn_cvt_pkrtz(ab.x, ab.y);
        Bf[m] = __builtin_amdgcn_cvt_pkrtz(ab.z, ab.w);
    }
    const float4 frw = ((const float4*)sPrepF)[lane];   // B-frag (16B/lane, LDS)
    const f16x8 bfrag = __builtin_bit_cast(f16x8, frw);
    const float bv = sBias[col16];
    f32x4 accB; accB[0] = bv; accB[1] = bv; accB[2] = bv; accB[3] = bv;

    // ---- MFMA MLP pass: 8 tiles of 16 samples, K=32, f16 in / f32 out ----
    auto mfma_pass = [&](auto tag) {
#pragma unroll
        for (int t = 0; t < 8; ++t) {
            float zs;
            if constexpr (decltype(tag)::fine) zs = sZf[t * 16 + col16];
            else                               zs = fmaf((float)(t * 16 + col16), dstep, nearv);
            const h16x2 z2 = __builtin_amdgcn_cvt_pkrtz(zs, zs);
            h16x2 h0 = pk_relu_f16(pk_fma_f16(Bf[0], z2, Af[0]));
            h16x2 h1 = pk_relu_f16(pk_fma_f16(Bf[1], z2, Af[1]));
            h16x2 h2 = pk_relu_f16(pk_fma_f16(Bf[2], z2, Af[2]));
            h16x2 h3 = pk_relu_f16(pk_fma_f16(Bf[3], z2, Af[3]));
            uint4 au;
            au.x = __builtin_bit_cast(unsigned int, h0);
            au.y = __builtin_bit_cast(unsigned int, h1);
            au.z = __builtin_bit_cast(unsigned int, h2);
            au.w = __builtin_bit_cast(unsigned int, h3);
            const f16x8 afrag = __builtin_bit_cast(f16x8, au);
            f32x4 acc = __builtin_amdgcn_mfma_f32_16x16x32_f16(afrag, bfrag, accB, 0, 0, 0);
            if (col16 < 5) {
#pragma unroll
                for (int i = 0; i < 4; ++i)
                    sStg[col16 * 132 + t * 16 + kb * 4 + i] = acc[i];
            }
        }
    };
    auto readback = [&](int p, float& sg, uint2& rgb) {
        const float c0 = sStg[0 * 132 + p];
        const float c1 = sStg[1 * 132 + p];
        const float c2 = sStg[2 * 132 + p];
        const float c3 = sStg[3 * 132 + p];
        const float c4 = sStg[4 * 132 + p];
        sg  = softplus_f(c0);
        rgb = pack_rgb(sigmoid_f(c1), sigmoid_f(c2), sigmoid_f(c3), sigmoid_f(c4));
    };

    // ---- coarse pass ----
    mfma_pass(CoarseTag{});
    __builtin_amdgcn_wave_barrier();
    float sgc0, sgc1; uint2 rc0, rc1;
    readback(2 * lane,     sgc0, rc0);
    readback(2 * lane + 1, sgc1, rc1);
    const float zc0 = fmaf((float)(2 * lane), dstep, nearv);
    const float zc1 = zc0 + dstep;
    __builtin_amdgcn_wave_barrier();    // stage consumed; cdf may overwrite

    // ---- coarse composite weights (for PDF) ----
    const float dc1 = (lane == 63) ? sample_dist : dstep;
    const float ec0 = __builtin_amdgcn_exp2f(dstep * sgc0 * -1.442695041f);
    const float ec1 = __builtin_amdgcn_exp2f(dc1 * sgc1 * -1.442695041f);
    const float alc0 = 1.f - ec0, alc1 = 1.f - ec1;
    const float vc0 = ec0 + 1e-15f, vc1 = ec1 + 1e-15f;
    const float incl = scan_mul_f(vc0 * vc1);
    float excl = __shfl_up(incl, 1, 64);
    if (lane == 0) excl = 1.f;
    const float wc0 = alc0 * excl;
    const float wc1 = alc1 * (excl * vc0);

    const float wnext = __shfl_down(wc0, 1, 64);      // w(2l+2)
    float p0 = wc1 + 1e-5f, p1 = wnext + 1e-5f;
    if (lane == 63) { p0 = 0.f; p1 = 0.f; }
    const float s01 = p0 + p1;
    const float cinc = scan_add_f(s01);
    const float total = __builtin_bit_cast(float,
        __builtin_amdgcn_readlane(__builtin_bit_cast(int, cinc), 63));
    const float rtot = __builtin_amdgcn_rcpf(total);
    const float cexcl = cinc - s01;
    if (lane < 63) {
        const float cdfA = (cexcl + p0) * rtot;
        const float cdfB = (cexcl + p0 + p1) * rtot;
        sCdf[2 * lane + 1] = cdfA;
        sCdf[2 * lane + 2] = cdfB;
        int cA = (int)ceilf(fmaf(128.f, cdfA, -0.5f));
        int cB = (int)ceilf(fmaf(128.f, cdfB, -0.5f));
        cA = min(max(cA, 0), 128); cB = min(max(cB, 0), 128);
        atomicAdd(&sHU[cA], 1);
        atomicAdd(&sHU[cB], 1);
    } else {
        sCdf[0] = 0.f;
        atomicAdd(&sHU[0], 1);
    }
    __builtin_amdgcn_wave_barrier();

    // ---- inds via histogram prefix; closed-form bin midpoints ----
    const int2 hu = *(const int2*)(sHU + 2 * lane);
    const int hs = hu.x + hu.y;
    const int hscan = scan_add_i(hs);
    const int hexcl = hscan - hs;
    const int indsA = hexcl + hu.x;
    const int indsB = hexcl + hs;

    auto lerp_z = [&](int inds, float u) -> float {
        const int below = inds - 1;
        const int above = min(inds, 126);
        const float cb = sCdf[below], ca = sCdf[above];
        const float bb = fmaf((float)below + 0.5f, dstep, nearv);
        const float ba = fmaf((float)above + 0.5f, dstep, nearv);
        float den = ca - cb;
        if (den < 1e-5f) den = 1.0f;
        const float t = (u - cb) * __builtin_amdgcn_rcpf(den);
        return bb + t * (ba - bb);
    };
    const float zf0 = lerp_z(indsA, ((float)(2 * lane) + 0.5f) * (1.0f / 128.f));
    const float zf1 = lerp_z(indsB, ((float)(2 * lane) + 1.5f) * (1.0f / 128.f));
    sZf[2 * lane]     = zf0;
    sZf[2 * lane + 1] = zf1;

    // rank of fine in coarse (closed form) + histogram
    const float inv_stepz = 127.0f / fmn;
    int r0 = (int)floorf((zf0 - nearv) * inv_stepz) + 1;
    int r1 = (int)floorf((zf1 - nearv) * inv_stepz) + 1;
    r0 = min(max(r0, 0), 128); r1 = min(max(r1, 0), 128);
    atomicAdd(&sHM[r0], 1);
    atomicAdd(&sHM[r1], 1);
    __builtin_amdgcn_wave_barrier();    // cdf consumed; fine stage may overwrite

    // ---- fine pass ----
    mfma_pass(FineTag{});
    __builtin_amdgcn_wave_barrier();
    float sgf0, sgf1; uint2 rf0, rf1;
    readback(2 * lane,     sgf0, rf0);
    readback(2 * lane + 1, sgf1, rf1);
    __builtin_amdgcn_wave_barrier();    // stage consumed before sorted writes

    // ---- merge ranks via histogram prefix; scatter sorted triples ----
    const int2 hm = *(const int2*)(sHM + 2 * lane);   // read precedes writes below
    const int ms = hm.x + hm.y;
    const int mscan = scan_add_i(ms);
    const int mexcl = mscan - ms;
    const int dC0 = 2 * lane + (mexcl + hm.x);
    const int dC1 = 2 * lane + 1 + (mexcl + ms);
    const int dF0 = 2 * lane + r0;
    const int dF1 = 2 * lane + 1 + r1;

    auto il = [](int d) { return ((d & 3) << 6) + (d >> 2); };
    {
        const int a0 = il(dC0), a1 = il(dC1), a2 = il(dF0), a3 = il(dF1);
        sZs[a0] = zc0; sSig[a0] = sgc0; sRgb[a0] = rc0;
        sZs[a1] = zc1; sSig[a1] = sgc1; sRgb[a1] = rc1;
        sZs[a2] = zf0; sSig[a2] = sgf0; sRgb[a2] = rf0;
        sZs[a3] = zf1; sSig[a3] = sgf1; sRgb[a3] = rf1;
    }
    __builtin_amdgcn_wave_barrier();

    // ---- final compositing: 4 sorted samples per lane (il4 reads) ----
    const float z0 = sZs[lane],        z1 = sZs[64 + lane];
    const float z2 = sZs[128 + lane],  z3 = sZs[192 + lane];
    const float g0 = sSig[lane],       g1 = sSig[64 + lane];
    const float g2 = sSig[128 + lane], g3 = sSig[192 + lane];
    const uint2 q0 = sRgb[lane],       q1 = sRgb[64 + lane];
    const uint2 q2 = sRgb[128 + lane], q3 = sRgb[192 + lane];

    const float znx = __shfl_down(z0, 1, 64);
    const float dd0 = z1 - z0;
    const float dd1 = z2 - z1;
    const float dd2 = z3 - z2;
    const float dd3 = (lane == 63) ? sample_dist : (znx - z3);

    const float e0 = __builtin_amdgcn_exp2f(dd0 * g0 * -1.442695041f);
    const float e1 = __builtin_amdgcn_exp2f(dd1 * g1 * -1.442695041f);
    const float e2 = __builtin_amdgcn_exp2f(dd2 * g2 * -1.442695041f);
    const float e3 = __builtin_amdgcn_exp2f(dd3 * g3 * -1.442695041f);
    const float al0 = 1.f - e0, al1 = 1.f - e1, al2 = 1.f - e2, al3 = 1.f - e3;
    const float v0 = e0 + 1e-15f, v1 = e1 + 1e-15f, v2 = e2 + 1e-15f, v3 = e3 + 1e-15f;

    const float incl2 = scan_mul_f(v0 * v1 * v2 * v3);
    float T0 = __shfl_up(incl2, 1, 64);
    if (lane == 0) T0 = 1.f;
    const float T1 = T0 * v0, T2 = T1 * v1, T3 = T2 * v2;
    const float w0 = al0 * T0, w1 = al1 * T1, w2 = al2 * T2, w3 = al3 * T3;

    const float inv_fn = 1.0f / fmn;
    const float oz0 = clampf((z0 - nearv) * inv_fn, 0.f, 1.f);
    const float oz1 = clampf((z1 - nearv) * inv_fn, 0.f, 1.f);
    const float oz2 = clampf((z2 - nearv) * inv_fn, 0.f, 1.f);
    const float oz3 = clampf((z3 - nearv) * inv_fn, 0.f, 1.f);

    float r0c[4], r1c[4], r2c[4], r3c[4];
    unpack_rgb(q0.x, q0.y, r0c);
    unpack_rgb(q1.x, q1.y, r1c);
    unpack_rgb(q2.x, q2.y, r2c);
    unpack_rgb(q3.x, q3.y, r3c);

    float vals[6];
#pragma unroll
    for (int c = 0; c < 4; ++c)
        vals[c] = w0 * r0c[c] + w1 * r1c[c] + w2 * r2c[c] + w3 * r3c[c];
    vals[4] = w0 * oz0 + w1 * oz1 + w2 * oz2 + w3 * oz3;
    vals[5] = w0 + w1 + w2 + w3;

#pragma unroll
    for (int q = 0; q < 6; ++q) vals[q] = scan_add_f(vals[q]);

    if (lane == 63) {
        const float wsum = vals[5];
#pragma unroll
        for (int c = 0; c < 4; ++c)
            out[ray * 4 + c] = vals[c] + (1.0f - wsum);
        out[4 * N_RAYS + ray] = vals[4];
        out[5 * N_RAYS + ray] = wsum;
    }
}

extern "C" void kernel_launch(void* const* d_in, const int* in_sizes, int n_in,
                              void* d_out, int out_size, void* d_ws, size_t ws_size,
                              hipStream_t stream) {
    const float* rays_o = (const float*)d_in[0];
    const float* rays_d = (const float*)d_in[1];
    const float* W1 = (const float*)d_in[2];
    const float* b1 = (const float*)d_in[3];
    const float* W2 = (const float*)d_in[4];
    const float* b2 = (const float*)d_in[5];
    const float* Wc = (const float*)d_in[6];
    const float* Wd = (const float*)d_in[7];
    const float* bc = (const float*)d_in[8];
    float* out = (float*)d_out;

    hipLaunchKernelGGL(nerf_render_kernel, dim3(N_RAYS / RPB), dim3(256), 0, stream,
                       rays_o, rays_d, W1, b1, W2, b2, Wc, bc, Wd, out);
}